// Round 25
// baseline (55.805 us; speedup 1.0000x reference)
//
#include <hip/hip_runtime.h>
#include <hip/hip_bf16.h>

// B=8, T=2048, E=1024, H=64
// Round 25: r22 base (54.45us best) with ONE proj change: K-tile 64->128,
// 8 steps, ring-2 x 80KB = 160KB LDS (the cap; attn already runs 160KB).
// Staging perfectly balanced (80 units / 8 waves = 10/wave). Pipeline:
// {vmcnt(0) drain of tile I (issued a FULL step earlier -> ~retired);
//  barrier; stage I+1 into the other buffer; compute I}. Convoys 16->8 --
// the one lever that has paid since the transaction fixes (r22: 32->16).
// attn (P-exchange) / wprep / reduce byte-identical to r22.
//
// Workspace: qb 2MB | kvb 4MB | partial 16MB | Wtb 384KB

typedef __attribute__((ext_vector_type(4))) float f32x4;
typedef __attribute__((ext_vector_type(4))) float float4_t;
typedef __attribute__((ext_vector_type(8))) short short8;
typedef __attribute__((ext_vector_type(4))) unsigned uint4_t;
typedef __attribute__((ext_vector_type(2))) unsigned uint2_t;

#define MFMA32(a, b, c) __builtin_amdgcn_mfma_f32_16x16x32_bf16(a, b, c, 0, 0, 0)

__device__ __forceinline__ short f2bf(float f) {
  unsigned u = __builtin_bit_cast(unsigned, f);
  unsigned r = (u + 0x7FFFu + ((u >> 16) & 1u)) >> 16;  // RNE
  return (short)r;
}

__device__ __forceinline__ unsigned cvt_pk_bf16(float lo, float hi) {
  unsigned r;
  asm volatile("v_cvt_pk_bf16_f32 %0, %1, %2" : "=v"(r) : "v"(lo), "v"(hi));
  return r;  // low16=bf16(lo), high16=bf16(hi)
}

__device__ __forceinline__ void gload16(const short* g, short* l) {
  __builtin_amdgcn_global_load_lds(
      (const __attribute__((address_space(1))) unsigned*)g,
      (__attribute__((address_space(3))) unsigned*)l, 16, 0, 0);
}

// ---------------- Kernel 0: W transpose+convert (unit-fragment-major) ----
// Wtb unit (kt 0..31, cf 0..11) at Wtb + (kt*12+cf)*512:
//   lane l (g=l>>4, lr=l&15) holds W_{wi}[kt*32+8g+j][n] for j=0..7,
//   wi = cf>>2, n = (cf&3)*16 + lr.
__global__ __launch_bounds__(256) void wprep_kernel(
    const float* __restrict__ Wq, const float* __restrict__ Wk,
    const float* __restrict__ Wv, short* __restrict__ Wtb) {
  int lin = blockIdx.x * 256 + threadIdx.x;  // 24576 threads = 384 units x 64
  int l = lin & 63;
  int cf = (lin >> 6) % 12;
  int kt = lin / 768;
  int g = l >> 4, lr = l & 15;
  int wi = cf >> 2;
  int n = ((cf & 3) << 4) + lr;
  const float* W = (wi == 0) ? Wq : (wi == 1) ? Wk : Wv;
  short* dst = Wtb + (size_t)(kt * 12 + cf) * 512 + l * 8;
#pragma unroll
  for (int j = 0; j < 8; j++) dst[j] = f2bf(W[(kt * 32 + g * 8 + j) * 64 + n]);
}

// ---------------- Kernel 1: pipelined QKV projection ----------------
// 256 blocks x 512 thr (8 waves). M=64 rows/block, K-tile=128, 8 steps,
// ring-2 x 80KB = 160KB. LDS tile = 80 units x 1KB:
//   u<32 : x units (f32), u = kh*8 + ur (kh 0..3): rows m0+ur*8..+7,
//          k-range k0+kh*32..+31, XOR-swizzled: lane l (ru=l>>3, c=l&7)
//          holds chunk (c^ru) of row ur*8+ru -> 8 FULL 128B lines/gload16.
//   u>=32: W units (bf16), u = 32 + kh*12 + cf; linear 1KB copy of Wtb
//          unit ((k0>>5)+kh, cf).
// Staging: wave w owns units w*10..w*10+9 (uniform 10/step).
// Wave (wr=w&3, wc=w>>2): 16 rows x 96 cols, acc[6]. k-bijection
// k = kh*32 + 8g + j for both operands -> contraction exact.
__device__ __forceinline__ void proj_stage(const float* __restrict__ x,
                                           const short* __restrict__ Wtb,
                                           short* dst, int m0, int k0, int w, int l) {
#pragma unroll
  for (int i = 0; i < 10; i++) {
    int u = w * 10 + i;  // 0..79, wave-uniform
    if (u < 32) {
      int kh = u >> 3, ur = u & 7;
      int ru = l >> 3, c = l & 7;
      const float* src = x + (size_t)(m0 + ur * 8 + ru) * 1024 + k0 + kh * 32 +
                         ((c ^ ru) << 2);
      gload16((const short*)src, dst + u * 512);
    } else {
      int uu = u - 32;  // 0..47
      int kh = uu / 12, cf = uu % 12;
      const short* src =
          Wtb + (size_t)(((k0 >> 5) + kh) * 12 + cf) * 512 + l * 8;  // linear
      gload16(src, dst + u * 512);
    }
  }
}

__device__ __forceinline__ void proj_compute(const short* __restrict__ ldsb,
                                             f32x4 (&acc)[6], int wr, int wc, int l) {
  const int g = l >> 4, lr = l & 15;
  const int ru = lr & 7;
#pragma unroll
  for (int kh = 0; kh < 4; kh++) {
    const int ub = (kh * 8 + wr * 2 + (lr >> 3)) * 512;  // x unit of row wr*16+lr
    // chunk 2g -> k slots kh*32+8g+0..3 ; 2g+1 -> +4..7 (swizzled slot)
    f32x4 fa = *(const f32x4*)&ldsb[ub + (ru * 8 + ((2 * g) ^ ru)) * 8];
    f32x4 fb = *(const f32x4*)&ldsb[ub + (ru * 8 + ((2 * g + 1) ^ ru)) * 8];
    uint4_t u_;
    u_[0] = cvt_pk_bf16(fa[0], fa[1]);
    u_[1] = cvt_pk_bf16(fa[2], fa[3]);
    u_[2] = cvt_pk_bf16(fb[0], fb[1]);
    u_[3] = cvt_pk_bf16(fb[2], fb[3]);
    short8 a = __builtin_bit_cast(short8, u_);
#pragma unroll
    for (int nf = 0; nf < 6; nf++) {
      int cf = wc * 6 + nf;
      short8 bfrag = *(const short8*)&ldsb[(32 + kh * 12 + cf) * 512 + l * 8];
      acc[nf] = MFMA32(a, bfrag, acc[nf]);
    }
  }
}

__global__ __launch_bounds__(512) void proj_kernel(
    const float* __restrict__ x, const short* __restrict__ Wtb,
    short* __restrict__ qb, short* __restrict__ kvb) {
  __shared__ __align__(16) short lds[2 * 80 * 512];  // 160KB ring-2 (the cap)
  const int tid = threadIdx.x;
  const int l = tid & 63, w = tid >> 6;
  const int g = l >> 4, lr = l & 15;
  const int wr = w & 3, wc = w >> 2;
  const int m0 = blockIdx.x * 64;

  f32x4 acc[6];
#pragma unroll
  for (int i = 0; i < 6; i++) acc[i] = (f32x4){0.f, 0.f, 0.f, 0.f};

  // prologue: tile 0 in flight (10 loads/wave)
  proj_stage(x, Wtb, lds, m0, 0, w, l);

  for (int I = 0; I < 8; I++) {
    // tile I's 10 loads were issued a full step earlier (prologue for I=0)
    // -> this drain is ~free; nothing younger is outstanding at this point.
    asm volatile("s_waitcnt vmcnt(0)" ::: "memory");
    __builtin_amdgcn_s_barrier();  // tile I visible to all waves; buffer
                                   // (I+1)&1 fully consumed -> restageable
    __builtin_amdgcn_sched_barrier(0);
    if (I + 1 < 8)
      proj_stage(x, Wtb, lds + ((I + 1) & 1) * 40960, m0, (I + 1) * 128, w, l);
    proj_compute(lds + (I & 1) * 40960, acc, wr, wc, l);
  }

  // epilogue: verified store formulas (wave = 16 rows x 96 cols)
#pragma unroll
  for (int nf = 0; nf < 6; nf++) {
    int colg0 = wc * 96 + nf * 16;
    int wi = colg0 >> 6;
    int d = (colg0 & 63) + lr;
    // fold 1/sqrt(H)*log2(e) into q so attn softmax uses 2^x directly
    float scale = (wi == 0) ? 0.18033688f : 1.0f;
#pragma unroll
    for (int r = 0; r < 4; r++) {
      int row = m0 + wr * 16 + g * 4 + r;
      int b = row >> 11, t = row & 2047;
      short bv = f2bf(acc[nf][r] * scale);
      if (wi == 0) {
        int idx = (((b * 128 + (t >> 4)) * 2 + (d >> 5)) * 64 +
                   ((((d >> 3) & 3) << 4) | (t & 15))) * 8 + (d & 7);
        qb[idx] = bv;
      } else if (wi == 1) {
        int u = (b << 2) | (((t >> 4) & 1) << 1) | (d >> 5);
        int idx = (((t >> 5) * 64 + u) << 9) +
                  ((((((d >> 3) & 3) << 4)) | (t & 15)) << 3) + (d & 7);
        kvb[idx] = bv;
      } else {
        int u = 32 + (b << 2) + (d >> 4);
        int idx = (((t >> 5) * 64 + u) << 9) +
                  (((((t >> 2) & 3) << 4) | (d & 15)) << 3) + (((t >> 4) & 1) << 2) + (t & 3);
        kvb[idx] = bv;
      }
    }
  }
}

// ---------------- Kernel 2: pipelined fused attention ----------------
__device__ __forceinline__ void stage_step(const short* __restrict__ kvb,
                                           short* lds_buf, int w, int l, int W) {
#pragma unroll
  for (int i = 0; i < 8; i++) {
    int u = w * 8 + i;
    const short* src = kvb + (((size_t)W * 64 + u) << 9) + l * 8;
    gload16(src, lds_buf + u * 512);
  }
}

// 256 blocks x 512 thr = 8 waves: tt = w>>1 (4 t-tiles of 16), dh = w&1.
// Block: 64 t-rows x one 256-s chunk; 8 steps of 32 s. sc = xcd (lin&7).
// Wave (tt,dh) computes QK+softmax only for the sf=dh 16-s half; P halves
// are swapped with partner wave w^1 via pxch under an lgkm-only barrier.
__global__ __launch_bounds__(512, 2) void attn_kernel(
    const short* __restrict__ qb, const short* __restrict__ kvb,
    short* __restrict__ partial) {
  __shared__ __align__(16) short lds[2][64 * 512];  // 128 KB K+V windows
  __shared__ __align__(16) uint2_t pxch[64 * 64];   // 32 KB: [(w*8+b)][l]
  const int tid = threadIdx.x;
  const int l = tid & 63, w = tid >> 6;
  const int tt = w >> 1, dh = w & 1;
  const int lin = blockIdx.x;     // 0..255
  const int sc = lin & 7;         // 0..7: per-XCD s-chunk of 256
  const int tblk = lin >> 3;      // 0..31
  const int tb16 = tblk * 4 + tt; // 0..127

  // Q hoisted: 16 x b128
  short8 qf[8][2];
#pragma unroll
  for (int b = 0; b < 8; b++)
#pragma unroll
    for (int ks = 0; ks < 2; ks++)
      qf[b][ks] = *(const short8*)&qb[(size_t)((b * 128 + tb16) * 2 + ks) * 512 + l * 8];

  f32x4 oacc[8][2];
#pragma unroll
  for (int b = 0; b < 8; b++)
#pragma unroll
    for (int n = 0; n < 2; n++) oacc[b][n] = (f32x4){0.f, 0.f, 0.f, 0.f};

  stage_step(kvb, &lds[0][0], w, l, sc * 8);

  for (int it = 0; it < 8; it++) {
    __syncthreads();  // drains step-old staging (free), publishes buf[it],
                      // and retires all pxch reads of the previous step.
    if (it + 1 < 8) stage_step(kvb, &lds[(it + 1) & 1][0], w, l, sc * 8 + it + 1);
    const short* ldsc = &lds[it & 1][0];

    // ---- QK^T for THIS wave's sf = dh half only (16 MFMA, 16 K-reads)
    f32x4 S[8];
    __builtin_amdgcn_s_setprio(1);
#pragma unroll
    for (int b = 0; b < 8; b++) {
      short8 kf0 = *(const short8*)&ldsc[(b * 4 + dh * 2 + 0) * 512 + l * 8];
      short8 kf1 = *(const short8*)&ldsc[(b * 4 + dh * 2 + 1) * 512 + l * 8];
      f32x4 s = (f32x4){0.f, 0.f, 0.f, 0.f};
      s = MFMA32(kf0, qf[b][0], s);
      s = MFMA32(kf1, qf[b][1], s);
      S[b] = s;
    }
    __builtin_amdgcn_s_setprio(0);
    // ---- softmax over batch for this half (32 exp)
#pragma unroll
    for (int r = 0; r < 4; r++) {
      float den = 0.f;
#pragma unroll
      for (int b = 0; b < 8; b++) {
        float e = __builtin_amdgcn_exp2f(S[b][r]);
        S[b][r] = e;
        den += e;
      }
      float inv = __builtin_amdgcn_rcpf(den);
#pragma unroll
      for (int b = 0; b < 8; b++) S[b][r] *= inv;
    }
    // ---- pack own half, publish to partner
    uint2_t pw[8];
#pragma unroll
    for (int b = 0; b < 8; b++) {
      pw[b][0] = cvt_pk_bf16(S[b][0], S[b][1]);
      pw[b][1] = cvt_pk_bf16(S[b][2], S[b][3]);
      pxch[(w * 8 + b) * 64 + l] = pw[b];
    }
    // lgkm-only barrier: ds_writes retired, staging vmcnt stays in flight
    asm volatile("s_waitcnt lgkmcnt(0)" ::: "memory");
    __builtin_amdgcn_s_barrier();
    __builtin_amdgcn_sched_barrier(0);
    // ---- read partner's half
    uint2_t pp[8];
#pragma unroll
    for (int b = 0; b < 8; b++) pp[b] = pxch[((w ^ 1) * 8 + b) * 64 + l];
    // ---- PV k=32: A = V unit (dh half), B = packed P (sf0|sf1)
    __builtin_amdgcn_s_setprio(1);
#pragma unroll
    for (int b = 0; b < 8; b++) {
      uint2_t lo = dh ? pp[b] : pw[b];   // sf=0 half
      uint2_t hi = dh ? pw[b] : pp[b];   // sf=1 half
      uint4_t pu;
      pu[0] = lo[0]; pu[1] = lo[1]; pu[2] = hi[0]; pu[3] = hi[1];
      short8 pbv = __builtin_bit_cast(short8, pu);
      short8 vf0 = *(const short8*)&ldsc[(32 + b * 4 + dh * 2 + 0) * 512 + l * 8];
      short8 vf1 = *(const short8*)&ldsc[(32 + b * 4 + dh * 2 + 1) * 512 + l * 8];
      oacc[b][0] = MFMA32(vf0, pbv, oacc[b][0]);
      oacc[b][1] = MFMA32(vf1, pbv, oacc[b][1]);
    }
    __builtin_amdgcn_s_setprio(0);
  }

  // store bf16 partial fragment-major (uint2/lane, wave-contiguous 512B runs)
  uint2_t* pout = (uint2_t*)partial;
#pragma unroll
  for (int b = 0; b < 8; b++)
#pragma unroll
    for (int n = 0; n < 2; n++) {
      int df = dh * 2 + n;
      uint2_t pk;
      pk[0] = cvt_pk_bf16(oacc[b][n][0], oacc[b][n][1]);
      pk[1] = cvt_pk_bf16(oacc[b][n][2], oacc[b][n][3]);
      pout[(size_t)(((sc * 8 + b) * 128 + tb16) * 4 + df) * 64 + l] = pk;
    }
}

// ---------------- Kernel 3: reduce bf16 partials -> f32 out ----------------
__global__ __launch_bounds__(256) void reduce_kernel(const short* __restrict__ partial,
                                                     float* __restrict__ out) {
  int i = blockIdx.x * 256 + threadIdx.x;  // 0..262143: (b,tb16,df,l)
  const uint2_t* p = (const uint2_t*)partial;
  float4_t a = (float4_t){0.f, 0.f, 0.f, 0.f};
  for (int sc = 0; sc < 8; sc++) {
    uint2_t v = p[(size_t)sc * 262144 + i];  // plain load: L2/L3-served
    a[0] += __builtin_bit_cast(float, v[0] << 16);
    a[1] += __builtin_bit_cast(float, v[0] & 0xFFFF0000u);
    a[2] += __builtin_bit_cast(float, v[1] << 16);
    a[3] += __builtin_bit_cast(float, v[1] & 0xFFFF0000u);
  }
  int b = i >> 15;
  int r1 = i & 32767;
  int tb16 = r1 >> 8;
  int r2 = r1 & 255;
  int df = r2 >> 6;
  int ll = r2 & 63;
  int gg = ll >> 4, lrr = ll & 15;
  float4_t o = a;
  __builtin_nontemporal_store(
      o, (float4_t*)&out[(size_t)(b * 2048 + tb16 * 16 + lrr) * 64 + df * 16 + gg * 4]);
}

extern "C" void kernel_launch(void* const* d_in, const int* in_sizes, int n_in,
                              void* d_out, int out_size, void* d_ws, size_t ws_size,
                              hipStream_t stream) {
  const float* x = (const float*)d_in[0];
  const float* Wq = (const float*)d_in[1];
  const float* Wk = (const float*)d_in[2];
  const float* Wv = (const float*)d_in[3];
  float* out = (float*)d_out;

  char* ws = (char*)d_ws;
  short* qb = (short*)ws;                     // 2MB
  short* kvb = qb + 16384 * 64;               // 4MB (64 windows x 64 units)
  short* partial = kvb + 2 * 16384 * 64;      // 16MB bf16 fragment-major
  short* Wtb = partial + 8ull * 262144 * 4;   // 384KB (unit-fragment-major)

  wprep_kernel<<<96, 256, 0, stream>>>(Wq, Wk, Wv, Wtb);
  proj_kernel<<<256, 512, 0, stream>>>(x, Wtb, qb, kvb);
  attn_kernel<<<256, 512, 0, stream>>>(qb, kvb, partial);
  reduce_kernel<<<1024, 256, 0, stream>>>(partial, out);
}

// Round 26
// 54.207 us; speedup vs baseline: 1.0295x; 1.0295x over previous
//
#include <hip/hip_runtime.h>
#include <hip/hip_bf16.h>

// B=8, T=2048, E=1024, H=64
// Round 26: revert to r22 (champion, 54.45us) verbatim. K-tile scan closed
// as a U-curve (32: 55.28 / 64: 54.45 / 128: 55.80) -> K64 ring-3 optimal.
// proj: M=64/block, K-tile=64, 16 steps, ring-3 x 40KB (120KB LDS),
//       uniform 5-unit/wave staging, counted vmcnt(5), 1 barrier/step,
//       W unit-fragment-major (linear 1KB loads), x 8-row x 128B XOR-swz.
// attn: 256 blk x 512 thr, fragment-major K/V windows, XCD decode, Q-hoist,
//       P-half exchange between dh-partner waves (lgkm-only barrier).
// reduce: 8-chunk bf16 partial -> f32 out.
//
// Workspace: qb 2MB | kvb 4MB | partial 16MB | Wtb 384KB

typedef __attribute__((ext_vector_type(4))) float f32x4;
typedef __attribute__((ext_vector_type(4))) float float4_t;
typedef __attribute__((ext_vector_type(8))) short short8;
typedef __attribute__((ext_vector_type(4))) unsigned uint4_t;
typedef __attribute__((ext_vector_type(2))) unsigned uint2_t;

#define MFMA32(a, b, c) __builtin_amdgcn_mfma_f32_16x16x32_bf16(a, b, c, 0, 0, 0)

__device__ __forceinline__ short f2bf(float f) {
  unsigned u = __builtin_bit_cast(unsigned, f);
  unsigned r = (u + 0x7FFFu + ((u >> 16) & 1u)) >> 16;  // RNE
  return (short)r;
}

__device__ __forceinline__ unsigned cvt_pk_bf16(float lo, float hi) {
  unsigned r;
  asm volatile("v_cvt_pk_bf16_f32 %0, %1, %2" : "=v"(r) : "v"(lo), "v"(hi));
  return r;  // low16=bf16(lo), high16=bf16(hi)
}

__device__ __forceinline__ void gload16(const short* g, short* l) {
  __builtin_amdgcn_global_load_lds(
      (const __attribute__((address_space(1))) unsigned*)g,
      (__attribute__((address_space(3))) unsigned*)l, 16, 0, 0);
}

// ---------------- Kernel 0: W transpose+convert (unit-fragment-major) ----
// Wtb unit (kt 0..31, cf 0..11) at Wtb + (kt*12+cf)*512:
//   lane l (g=l>>4, lr=l&15) holds W_{wi}[kt*32+8g+j][n] for j=0..7,
//   wi = cf>>2, n = (cf&3)*16 + lr.
__global__ __launch_bounds__(256) void wprep_kernel(
    const float* __restrict__ Wq, const float* __restrict__ Wk,
    const float* __restrict__ Wv, short* __restrict__ Wtb) {
  int lin = blockIdx.x * 256 + threadIdx.x;  // 24576 threads = 384 units x 64
  int l = lin & 63;
  int cf = (lin >> 6) % 12;
  int kt = lin / 768;
  int g = l >> 4, lr = l & 15;
  int wi = cf >> 2;
  int n = ((cf & 3) << 4) + lr;
  const float* W = (wi == 0) ? Wq : (wi == 1) ? Wk : Wv;
  short* dst = Wtb + (size_t)(kt * 12 + cf) * 512 + l * 8;
#pragma unroll
  for (int j = 0; j < 8; j++) dst[j] = f2bf(W[(kt * 32 + g * 8 + j) * 64 + n]);
}

// ---------------- Kernel 1: pipelined QKV projection ----------------
// 256 blocks x 512 thr (8 waves). M=64 rows/block, K-tile=64, ring-3 120KB.
// LDS tile = 40 units x 1KB:
//   u<16 : x units (f32), u = kh*8 + ur: rows m0+ur*8..+7, k-half kh,
//          XOR-swizzled: lane l (ru=l>>3, c=l&7) holds chunk (c^ru) of row
//          ur*8+ru -> each gload16 reads 8 FULL 128B lines.
//   u>=16: W units (bf16), u = 16 + kh*12 + cf; linear 1KB copy of Wtb
//          unit ((k0>>5)+kh, cf).
// Staging: wave w owns units w*5..w*5+4 (uniform 5/step).
// Wave (wr=w&3, wc=w>>2): 16 rows x 96 cols, acc[6]. k-bijection
// k = kh*32 + 8g + j for both operands -> contraction exact.
__device__ __forceinline__ void proj_stage(const float* __restrict__ x,
                                           const short* __restrict__ Wtb,
                                           short* dst, int m0, int k0, int w, int l) {
#pragma unroll
  for (int i = 0; i < 5; i++) {
    int u = w * 5 + i;  // 0..39, wave-uniform
    if (u < 16) {
      int kh = u >> 3, ur = u & 7;
      int ru = l >> 3, c = l & 7;
      const float* src = x + (size_t)(m0 + ur * 8 + ru) * 1024 + k0 + kh * 32 +
                         ((c ^ ru) << 2);
      gload16((const short*)src, dst + u * 512);
    } else {
      int uu = u - 16;  // 0..23
      int kh = uu / 12, cf = uu % 12;
      const short* src =
          Wtb + (size_t)(((k0 >> 5) + kh) * 12 + cf) * 512 + l * 8;  // linear
      gload16(src, dst + u * 512);
    }
  }
}

__device__ __forceinline__ void proj_compute(const short* __restrict__ ldsb,
                                             f32x4 (&acc)[6], int wr, int wc, int l) {
  const int g = l >> 4, lr = l & 15;
  const int ru = lr & 7;
#pragma unroll
  for (int kh = 0; kh < 2; kh++) {
    const int ub = (kh * 8 + wr * 2 + (lr >> 3)) * 512;  // x unit of row wr*16+lr
    // chunk 2g -> k slots kh*32+8g+0..3 ; 2g+1 -> +4..7 (swizzled slot)
    f32x4 fa = *(const f32x4*)&ldsb[ub + (ru * 8 + ((2 * g) ^ ru)) * 8];
    f32x4 fb = *(const f32x4*)&ldsb[ub + (ru * 8 + ((2 * g + 1) ^ ru)) * 8];
    uint4_t u_;
    u_[0] = cvt_pk_bf16(fa[0], fa[1]);
    u_[1] = cvt_pk_bf16(fa[2], fa[3]);
    u_[2] = cvt_pk_bf16(fb[0], fb[1]);
    u_[3] = cvt_pk_bf16(fb[2], fb[3]);
    short8 a = __builtin_bit_cast(short8, u_);
#pragma unroll
    for (int nf = 0; nf < 6; nf++) {
      int cf = wc * 6 + nf;
      short8 bfrag = *(const short8*)&ldsb[(16 + kh * 12 + cf) * 512 + l * 8];
      acc[nf] = MFMA32(a, bfrag, acc[nf]);
    }
  }
}

__global__ __launch_bounds__(512) void proj_kernel(
    const float* __restrict__ x, const short* __restrict__ Wtb,
    short* __restrict__ qb, short* __restrict__ kvb) {
  __shared__ __align__(16) short lds[3 * 40 * 512];  // 120KB ring-3
  const int tid = threadIdx.x;
  const int l = tid & 63, w = tid >> 6;
  const int g = l >> 4, lr = l & 15;
  const int wr = w & 3, wc = w >> 2;
  const int m0 = blockIdx.x * 64;

  f32x4 acc[6];
#pragma unroll
  for (int i = 0; i < 6; i++) acc[i] = (f32x4){0.f, 0.f, 0.f, 0.f};

  // prologue: tiles 0,1 in flight (10 loads/wave)
  proj_stage(x, Wtb, lds, m0, 0, w, l);
  proj_stage(x, Wtb, lds + 20480, m0, 64, w, l);

  for (int I = 0; I < 16; I++) {
    // outstanding at top: rem(tile I: 5) + 5 (tile I+1) -> vmcnt(5) == tile
    // I landed (tail I=15: nothing younger -> vmcnt(0)).
    if (I < 15) { asm volatile("s_waitcnt vmcnt(5)" ::: "memory"); }
    else        { asm volatile("s_waitcnt vmcnt(0)" ::: "memory"); }
    __builtin_amdgcn_s_barrier();  // also: all waves done computing tile I-1
                                   // -> buffer (I+2)%3 is free to restage
    __builtin_amdgcn_sched_barrier(0);
    if (I + 2 < 16)
      proj_stage(x, Wtb, lds + ((I + 2) % 3) * 20480, m0, (I + 2) * 64, w, l);
    proj_compute(lds + (I % 3) * 20480, acc, wr, wc, l);
  }

  // epilogue: verified store formulas (wave = 16 rows x 96 cols)
#pragma unroll
  for (int nf = 0; nf < 6; nf++) {
    int colg0 = wc * 96 + nf * 16;
    int wi = colg0 >> 6;
    int d = (colg0 & 63) + lr;
    // fold 1/sqrt(H)*log2(e) into q so attn softmax uses 2^x directly
    float scale = (wi == 0) ? 0.18033688f : 1.0f;
#pragma unroll
    for (int r = 0; r < 4; r++) {
      int row = m0 + wr * 16 + g * 4 + r;
      int b = row >> 11, t = row & 2047;
      short bv = f2bf(acc[nf][r] * scale);
      if (wi == 0) {
        int idx = (((b * 128 + (t >> 4)) * 2 + (d >> 5)) * 64 +
                   ((((d >> 3) & 3) << 4) | (t & 15))) * 8 + (d & 7);
        qb[idx] = bv;
      } else if (wi == 1) {
        int u = (b << 2) | (((t >> 4) & 1) << 1) | (d >> 5);
        int idx = (((t >> 5) * 64 + u) << 9) +
                  ((((((d >> 3) & 3) << 4)) | (t & 15)) << 3) + (d & 7);
        kvb[idx] = bv;
      } else {
        int u = 32 + (b << 2) + (d >> 4);
        int idx = (((t >> 5) * 64 + u) << 9) +
                  (((((t >> 2) & 3) << 4) | (d & 15)) << 3) + (((t >> 4) & 1) << 2) + (t & 3);
        kvb[idx] = bv;
      }
    }
  }
}

// ---------------- Kernel 2: pipelined fused attention ----------------
__device__ __forceinline__ void stage_step(const short* __restrict__ kvb,
                                           short* lds_buf, int w, int l, int W) {
#pragma unroll
  for (int i = 0; i < 8; i++) {
    int u = w * 8 + i;
    const short* src = kvb + (((size_t)W * 64 + u) << 9) + l * 8;
    gload16(src, lds_buf + u * 512);
  }
}

// 256 blocks x 512 thr = 8 waves: tt = w>>1 (4 t-tiles of 16), dh = w&1.
// Block: 64 t-rows x one 256-s chunk; 8 steps of 32 s. sc = xcd (lin&7).
// Wave (tt,dh) computes QK+softmax only for the sf=dh 16-s half; P halves
// are swapped with partner wave w^1 via pxch under an lgkm-only barrier.
__global__ __launch_bounds__(512, 2) void attn_kernel(
    const short* __restrict__ qb, const short* __restrict__ kvb,
    short* __restrict__ partial) {
  __shared__ __align__(16) short lds[2][64 * 512];  // 128 KB K+V windows
  __shared__ __align__(16) uint2_t pxch[64 * 64];   // 32 KB: [(w*8+b)][l]
  const int tid = threadIdx.x;
  const int l = tid & 63, w = tid >> 6;
  const int tt = w >> 1, dh = w & 1;
  const int lin = blockIdx.x;     // 0..255
  const int sc = lin & 7;         // 0..7: per-XCD s-chunk of 256
  const int tblk = lin >> 3;      // 0..31
  const int tb16 = tblk * 4 + tt; // 0..127

  // Q hoisted: 16 x b128
  short8 qf[8][2];
#pragma unroll
  for (int b = 0; b < 8; b++)
#pragma unroll
    for (int ks = 0; ks < 2; ks++)
      qf[b][ks] = *(const short8*)&qb[(size_t)((b * 128 + tb16) * 2 + ks) * 512 + l * 8];

  f32x4 oacc[8][2];
#pragma unroll
  for (int b = 0; b < 8; b++)
#pragma unroll
    for (int n = 0; n < 2; n++) oacc[b][n] = (f32x4){0.f, 0.f, 0.f, 0.f};

  stage_step(kvb, &lds[0][0], w, l, sc * 8);

  for (int it = 0; it < 8; it++) {
    __syncthreads();  // drains step-old staging (free), publishes buf[it],
                      // and retires all pxch reads of the previous step.
    if (it + 1 < 8) stage_step(kvb, &lds[(it + 1) & 1][0], w, l, sc * 8 + it + 1);
    const short* ldsc = &lds[it & 1][0];

    // ---- QK^T for THIS wave's sf = dh half only (16 MFMA, 16 K-reads)
    f32x4 S[8];
    __builtin_amdgcn_s_setprio(1);
#pragma unroll
    for (int b = 0; b < 8; b++) {
      short8 kf0 = *(const short8*)&ldsc[(b * 4 + dh * 2 + 0) * 512 + l * 8];
      short8 kf1 = *(const short8*)&ldsc[(b * 4 + dh * 2 + 1) * 512 + l * 8];
      f32x4 s = (f32x4){0.f, 0.f, 0.f, 0.f};
      s = MFMA32(kf0, qf[b][0], s);
      s = MFMA32(kf1, qf[b][1], s);
      S[b] = s;
    }
    __builtin_amdgcn_s_setprio(0);
    // ---- softmax over batch for this half (32 exp)
#pragma unroll
    for (int r = 0; r < 4; r++) {
      float den = 0.f;
#pragma unroll
      for (int b = 0; b < 8; b++) {
        float e = __builtin_amdgcn_exp2f(S[b][r]);
        S[b][r] = e;
        den += e;
      }
      float inv = __builtin_amdgcn_rcpf(den);
#pragma unroll
      for (int b = 0; b < 8; b++) S[b][r] *= inv;
    }
    // ---- pack own half, publish to partner
    uint2_t pw[8];
#pragma unroll
    for (int b = 0; b < 8; b++) {
      pw[b][0] = cvt_pk_bf16(S[b][0], S[b][1]);
      pw[b][1] = cvt_pk_bf16(S[b][2], S[b][3]);
      pxch[(w * 8 + b) * 64 + l] = pw[b];
    }
    // lgkm-only barrier: ds_writes retired, staging vmcnt stays in flight
    asm volatile("s_waitcnt lgkmcnt(0)" ::: "memory");
    __builtin_amdgcn_s_barrier();
    __builtin_amdgcn_sched_barrier(0);
    // ---- read partner's half
    uint2_t pp[8];
#pragma unroll
    for (int b = 0; b < 8; b++) pp[b] = pxch[((w ^ 1) * 8 + b) * 64 + l];
    // ---- PV k=32: A = V unit (dh half), B = packed P (sf0|sf1)
    __builtin_amdgcn_s_setprio(1);
#pragma unroll
    for (int b = 0; b < 8; b++) {
      uint2_t lo = dh ? pp[b] : pw[b];   // sf=0 half
      uint2_t hi = dh ? pw[b] : pp[b];   // sf=1 half
      uint4_t pu;
      pu[0] = lo[0]; pu[1] = lo[1]; pu[2] = hi[0]; pu[3] = hi[1];
      short8 pbv = __builtin_bit_cast(short8, pu);
      short8 vf0 = *(const short8*)&ldsc[(32 + b * 4 + dh * 2 + 0) * 512 + l * 8];
      short8 vf1 = *(const short8*)&ldsc[(32 + b * 4 + dh * 2 + 1) * 512 + l * 8];
      oacc[b][0] = MFMA32(vf0, pbv, oacc[b][0]);
      oacc[b][1] = MFMA32(vf1, pbv, oacc[b][1]);
    }
    __builtin_amdgcn_s_setprio(0);
  }

  // store bf16 partial fragment-major (uint2/lane, wave-contiguous 512B runs)
  uint2_t* pout = (uint2_t*)partial;
#pragma unroll
  for (int b = 0; b < 8; b++)
#pragma unroll
    for (int n = 0; n < 2; n++) {
      int df = dh * 2 + n;
      uint2_t pk;
      pk[0] = cvt_pk_bf16(oacc[b][n][0], oacc[b][n][1]);
      pk[1] = cvt_pk_bf16(oacc[b][n][2], oacc[b][n][3]);
      pout[(size_t)(((sc * 8 + b) * 128 + tb16) * 4 + df) * 64 + l] = pk;
    }
}

// ---------------- Kernel 3: reduce bf16 partials -> f32 out ----------------
__global__ __launch_bounds__(256) void reduce_kernel(const short* __restrict__ partial,
                                                     float* __restrict__ out) {
  int i = blockIdx.x * 256 + threadIdx.x;  // 0..262143: (b,tb16,df,l)
  const uint2_t* p = (const uint2_t*)partial;
  float4_t a = (float4_t){0.f, 0.f, 0.f, 0.f};
  for (int sc = 0; sc < 8; sc++) {
    uint2_t v = p[(size_t)sc * 262144 + i];  // plain load: L2/L3-served
    a[0] += __builtin_bit_cast(float, v[0] << 16);
    a[1] += __builtin_bit_cast(float, v[0] & 0xFFFF0000u);
    a[2] += __builtin_bit_cast(float, v[1] << 16);
    a[3] += __builtin_bit_cast(float, v[1] & 0xFFFF0000u);
  }
  int b = i >> 15;
  int r1 = i & 32767;
  int tb16 = r1 >> 8;
  int r2 = r1 & 255;
  int df = r2 >> 6;
  int ll = r2 & 63;
  int gg = ll >> 4, lrr = ll & 15;
  float4_t o = a;
  __builtin_nontemporal_store(
      o, (float4_t*)&out[(size_t)(b * 2048 + tb16 * 16 + lrr) * 64 + df * 16 + gg * 4]);
}

extern "C" void kernel_launch(void* const* d_in, const int* in_sizes, int n_in,
                              void* d_out, int out_size, void* d_ws, size_t ws_size,
                              hipStream_t stream) {
  const float* x = (const float*)d_in[0];
  const float* Wq = (const float*)d_in[1];
  const float* Wk = (const float*)d_in[2];
  const float* Wv = (const float*)d_in[3];
  float* out = (float*)d_out;

  char* ws = (char*)d_ws;
  short* qb = (short*)ws;                     // 2MB
  short* kvb = qb + 16384 * 64;               // 4MB (64 windows x 64 units)
  short* partial = kvb + 2 * 16384 * 64;      // 16MB bf16 fragment-major
  short* Wtb = partial + 8ull * 262144 * 4;   // 384KB (unit-fragment-major)

  wprep_kernel<<<96, 256, 0, stream>>>(Wq, Wk, Wv, Wtb);
  proj_kernel<<<256, 512, 0, stream>>>(x, Wtb, qb, kvb);
  attn_kernel<<<256, 512, 0, stream>>>(qb, kvb, partial);
  reduce_kernel<<<1024, 256, 0, stream>>>(partial, out);
}